// Round 1
// baseline (250.340 us; speedup 1.0000x reference)
//
#include <hip/hip_runtime.h>
#include <hip/hip_bf16.h>

#define B_   2
#define S_   4096
#define D_   256
#define H_   4
#define DH_  64
#define BH_  (B_*H_)
#define NTOK (BH_*S_*DH_)   // 2,097,152 elements per Q/K/V buffer

typedef short v8s __attribute__((ext_vector_type(8)));
typedef float v4f __attribute__((ext_vector_type(4)));

static __device__ __forceinline__ short f2bf(float f) {
    __hip_bfloat16 h = __float2bfloat16(f);
    return *reinterpret_cast<short*>(&h);
}

// ---------------------------------------------------------------------------
// Kernel 1: fused QKV projection (fp32 compute), outputs bf16.
//   Q:  [BH][S][DH]  (pre-scaled by 1/sqrt(DH))
//   K:  [BH][S][DH]
//   Vt: [BH][DH][S]  (transposed so PV B-fragments are contiguous)
// Block: 256 threads, handles one (b,h) and 32 sequence rows.
// ---------------------------------------------------------------------------
__global__ __launch_bounds__(256) void qkv_proj_kernel(
    const float* __restrict__ x,
    const float* __restrict__ qw, const float* __restrict__ qb,
    const float* __restrict__ kw, const float* __restrict__ kb,
    const float* __restrict__ vw, const float* __restrict__ vb,
    short* __restrict__ Qo, short* __restrict__ Ko, short* __restrict__ Vt)
{
    // +1 pad: lane-indexed row reads wq[e][d] hit banks (e+d)%32 -> conflict-free
    __shared__ float wq[DH_][DH_+1];
    __shared__ float wk[DH_][DH_+1];
    __shared__ float wv[DH_][DH_+1];
    __shared__ float xs[32][DH_];      // broadcast reads only -> no pad needed

    const int t  = threadIdx.x;
    const int bh = blockIdx.y;
    const int h  = bh & (H_-1);
    const int b  = bh >> 2;
    const int s0 = blockIdx.x * 32;

    const float* qwh = qw + h*DH_*DH_;
    const float* kwh = kw + h*DH_*DH_;
    const float* vwh = vw + h*DH_*DH_;

    #pragma unroll
    for (int i = 0; i < 16; ++i) {
        int idx = t + i*256;            // 0..4095
        int e = idx >> 6, d = idx & 63;
        wq[e][d] = qwh[idx];
        wk[e][d] = kwh[idx];
        wv[e][d] = vwh[idx];
    }
    #pragma unroll
    for (int i = 0; i < 8; ++i) {
        int idx = t + i*256;            // 0..2047
        int r = idx >> 6, d = idx & 63;
        xs[r][d] = x[((size_t)(b*S_ + s0 + r))*D_ + h*DH_ + d];
    }
    __syncthreads();

    const int e  = t & 63;              // output feature (== lane)
    const int wg = t >> 6;              // wave id 0..3 -> rows wg*8..wg*8+7
    float aq[8], ak[8], av[8];
    #pragma unroll
    for (int i = 0; i < 8; ++i) { aq[i] = 0.f; ak[i] = 0.f; av[i] = 0.f; }

    for (int d = 0; d < DH_; ++d) {
        float wqv = wq[e][d], wkv = wk[e][d], wvv = wv[e][d];
        #pragma unroll
        for (int i = 0; i < 8; ++i) {
            float xv = xs[wg*8 + i][d];     // wave-broadcast
            aq[i] = fmaf(xv, wqv, aq[i]);
            ak[i] = fmaf(xv, wkv, ak[i]);
            av[i] = fmaf(xv, wvv, av[i]);
        }
    }

    const float qbe = qb[h*DH_ + e], kbe = kb[h*DH_ + e], vbe = vb[h*DH_ + e];
    #pragma unroll
    for (int i = 0; i < 8; ++i) {
        int s = s0 + wg*8 + i;
        float qv = (aq[i] + qbe) * 0.125f;   // fold 1/sqrt(64) into Q
        float kv = ak[i] + kbe;
        float vv = av[i] + vbe;
        size_t base = ((size_t)bh*S_ + s)*DH_ + e;
        Qo[base] = f2bf(qv);
        Ko[base] = f2bf(kv);
        Vt[((size_t)bh*DH_ + e)*S_ + s] = f2bf(vv);
    }
}

// ---------------------------------------------------------------------------
// Kernel 2: flash attention, bf16 MFMA 16x16x32, fp32 online softmax.
// Block: 256 threads = 4 waves; wave w owns q-rows [blockIdx.x*64 + w*16, +16).
// KV processed in tiles of 32 keys.
// Fragment layouts (verified m91/m97/m89):
//   A/B frag: element [row = lane&15][k = (lane>>4)*8 + j], j=0..7
//   C/D:      col = lane&15, row = (lane>>4)*4 + reg
// ---------------------------------------------------------------------------
__global__ __launch_bounds__(256) void attn_kernel(
    const short* __restrict__ Q, const short* __restrict__ K,
    const short* __restrict__ Vt, float* __restrict__ out)
{
    __shared__ __hip_bfloat16 pl[4][16][32];   // per-wave P tile (D-layout -> A-layout relay)

    const int t  = threadIdx.x;
    const int w  = t >> 6;
    const int l  = t & 63;
    const int lr = l & 15;     // frag row / D col
    const int lg = l >> 4;     // 0..3
    const int bh = blockIdx.y;
    const int h  = bh & 3;
    const int b  = bh >> 2;
    const int q0 = blockIdx.x*64 + w*16;

    const short* Qh = Q  + (size_t)bh*S_*DH_;
    const short* Kh = K  + (size_t)bh*S_*DH_;
    const short* Vh = Vt + (size_t)bh*DH_*S_;

    // Q fragments for this wave's 16 rows (K-contraction over DH=64 -> 2 frags)
    v8s aq0 = *(const v8s*)(Qh + (q0 + lr)*DH_ + lg*8);
    v8s aq1 = *(const v8s*)(Qh + (q0 + lr)*DH_ + lg*8 + 32);

    v4f o0 = {0.f,0.f,0.f,0.f}, o1 = {0.f,0.f,0.f,0.f};
    v4f o2 = {0.f,0.f,0.f,0.f}, o3 = {0.f,0.f,0.f,0.f};
    float mrow[4], lrow[4];
    #pragma unroll
    for (int r = 0; r < 4; ++r) { mrow[r] = -INFINITY; lrow[r] = 0.f; }

    for (int kv0 = 0; kv0 < S_; kv0 += 32) {
        // --- QK^T: S[16 q x 32 kv] in two accumulators ---
        const short* kp = Kh + (kv0 + lr)*DH_ + lg*8;
        v8s bk00 = *(const v8s*)(kp);
        v8s bk01 = *(const v8s*)(kp + 32);
        v8s bk10 = *(const v8s*)(kp + 16*DH_);
        v8s bk11 = *(const v8s*)(kp + 16*DH_ + 32);

        v4f s0 = {0.f,0.f,0.f,0.f};
        s0 = __builtin_amdgcn_mfma_f32_16x16x32_bf16(aq0, bk00, s0, 0, 0, 0);
        s0 = __builtin_amdgcn_mfma_f32_16x16x32_bf16(aq1, bk01, s0, 0, 0, 0);
        v4f s1 = {0.f,0.f,0.f,0.f};
        s1 = __builtin_amdgcn_mfma_f32_16x16x32_bf16(aq0, bk10, s1, 0, 0, 0);
        s1 = __builtin_amdgcn_mfma_f32_16x16x32_bf16(aq1, bk11, s1, 0, 0, 0);

        // --- online softmax (fp32). Row r_glob = lg*4 + r; 16 lanes (lr) hold cols ---
        float sc[4];
        #pragma unroll
        for (int r = 0; r < 4; ++r) {
            float a = s0[r], c = s1[r];
            float mx = fmaxf(a, c);
            mx = fmaxf(mx, __shfl_xor(mx, 1));
            mx = fmaxf(mx, __shfl_xor(mx, 2));
            mx = fmaxf(mx, __shfl_xor(mx, 4));
            mx = fmaxf(mx, __shfl_xor(mx, 8));
            float mn    = fmaxf(mrow[r], mx);
            float scale = __expf(mrow[r] - mn);
            float p0 = __expf(a - mn);
            float p1 = __expf(c - mn);
            float ps = p0 + p1;
            ps += __shfl_xor(ps, 1);
            ps += __shfl_xor(ps, 2);
            ps += __shfl_xor(ps, 4);
            ps += __shfl_xor(ps, 8);
            lrow[r] = lrow[r]*scale + ps;
            mrow[r] = mn;
            sc[r]   = scale;
            int row = lg*4 + r;
            pl[w][row][lr]      = __float2bfloat16(p0);
            pl[w][row][16 + lr] = __float2bfloat16(p1);
        }
        #pragma unroll
        for (int r = 0; r < 4; ++r) {
            o0[r] *= sc[r]; o1[r] *= sc[r]; o2[r] *= sc[r]; o3[r] *= sc[r];
        }

        // wave-private LDS relay: writes retire in-order before reads; wait anyway
        asm volatile("s_waitcnt lgkmcnt(0)" ::: "memory");
        __builtin_amdgcn_sched_barrier(0);

        // --- PV: O[16 q x 64 d] += P[16 x 32] * V[32 x 64] ---
        v8s ap = *(const v8s*)(&pl[w][lr][lg*8]);
        const short* vp = Vh + lr*S_ + kv0 + lg*8;   // Vt[d][kv]
        v8s bv0 = *(const v8s*)(vp);
        v8s bv1 = *(const v8s*)(vp + 16*S_);
        v8s bv2 = *(const v8s*)(vp + 32*S_);
        v8s bv3 = *(const v8s*)(vp + 48*S_);
        o0 = __builtin_amdgcn_mfma_f32_16x16x32_bf16(ap, bv0, o0, 0, 0, 0);
        o1 = __builtin_amdgcn_mfma_f32_16x16x32_bf16(ap, bv1, o1, 0, 0, 0);
        o2 = __builtin_amdgcn_mfma_f32_16x16x32_bf16(ap, bv2, o2, 0, 0, 0);
        o3 = __builtin_amdgcn_mfma_f32_16x16x32_bf16(ap, bv3, o3, 0, 0, 0);
    }

    // --- epilogue: normalize and store fp32 output [B][S][D] ---
    #pragma unroll
    for (int r = 0; r < 4; ++r) {
        int s = q0 + lg*4 + r;
        float inv = 1.f / lrow[r];
        float* op = out + ((size_t)b*S_ + s)*D_ + h*DH_ + lr;
        op[0]  = o0[r]*inv;
        op[16] = o1[r]*inv;
        op[32] = o2[r]*inv;
        op[48] = o3[r]*inv;
    }
}

extern "C" void kernel_launch(void* const* d_in, const int* in_sizes, int n_in,
                              void* d_out, int out_size, void* d_ws, size_t ws_size,
                              hipStream_t stream)
{
    const float* x  = (const float*)d_in[0];
    const float* qw = (const float*)d_in[1];
    const float* qb = (const float*)d_in[2];
    const float* kw = (const float*)d_in[3];
    const float* kb = (const float*)d_in[4];
    const float* vw = (const float*)d_in[5];
    const float* vb = (const float*)d_in[6];
    // d_in[7] = train flag, unused (inference path only)

    short* Qb = (short*)d_ws;           // bf16 [BH][S][DH]
    short* Kb = Qb + NTOK;              // bf16 [BH][S][DH]
    short* Vt = Kb + NTOK;              // bf16 [BH][DH][S]
    float* out = (float*)d_out;

    dim3 pg(S_/32, BH_), pb(256);
    hipLaunchKernelGGL(qkv_proj_kernel, pg, pb, 0, stream,
                       x, qw, qb, kw, kb, vw, vb, Qb, Kb, Vt);

    dim3 ag(S_/64, BH_), ab(256);
    hipLaunchKernelGGL(attn_kernel, ag, ab, 0, stream, Qb, Kb, Vt, out);
}

// Round 2
// 111.914 us; speedup vs baseline: 2.2369x; 2.2369x over previous
//
#include <hip/hip_runtime.h>
#include <hip/hip_bf16.h>

// MSA: B=2, S=4096, D=256, H=4, DH=64. fp32 in/out, bf16 MFMA internally.
// R2: swapped-QK^T 32x32 flash attention, 8 waves/block, KVBLK=64,
//     LDS double-buffer + XOR swizzle, 2-way KV split + combine.

#define B_   2
#define S_   4096
#define D_   256
#define H_   4
#define DH_  64
#define BH_  8
#define NTOK (BH_*S_*DH_)   // elements per Q/K/V buffer

#define KVB  64             // kv tile per step
#define QW   32             // q rows per wave
#define NW   8              // waves per block
#define QB   (QW*NW)        // 256 q rows per block
#define NINST (BH_*(S_/QW)) // 1024 q-wave instances

typedef short v8s __attribute__((ext_vector_type(8)));
typedef float v16f __attribute__((ext_vector_type(16)));
typedef float v4f __attribute__((ext_vector_type(4)));
typedef unsigned v4u __attribute__((ext_vector_type(4)));

#define QSCL (0.125f * 1.4426950408889634f)   // 1/sqrt(64) * log2(e): exp2 domain

static __device__ __forceinline__ short f2bf(float f) {
    __hip_bfloat16 h = __float2bfloat16(f);
    return *reinterpret_cast<short*>(&h);
}
static __device__ __forceinline__ unsigned cvtpk(float lo, float hi) {
    unsigned r;
    asm("v_cvt_pk_bf16_f32 %0, %1, %2" : "=v"(r) : "v"(lo), "v"(hi));
    return r;
}
static __device__ __forceinline__ v16f vz16() {
    v16f z;
    #pragma unroll
    for (int i = 0; i < 16; ++i) z[i] = 0.f;
    return z;
}

// ---------------------------------------------------------------------------
// Kernel 1: fused QKV projection (fp32 compute) -> bf16.
//   Q: [BH][S][DH] pre-scaled by QSCL; K: [BH][S][DH]; Vt: [BH][DH][S].
// ---------------------------------------------------------------------------
__global__ __launch_bounds__(256) void qkv_proj_kernel(
    const float* __restrict__ x,
    const float* __restrict__ qw, const float* __restrict__ qb,
    const float* __restrict__ kw, const float* __restrict__ kb,
    const float* __restrict__ vw, const float* __restrict__ vb,
    short* __restrict__ Qo, short* __restrict__ Ko, short* __restrict__ Vt)
{
    __shared__ float wq[DH_][DH_+1];
    __shared__ float wk[DH_][DH_+1];
    __shared__ float wv[DH_][DH_+1];
    __shared__ float xs[32][DH_];

    const int t  = threadIdx.x;
    const int bh = blockIdx.y;
    const int h  = bh & (H_-1);
    const int b  = bh >> 2;
    const int s0 = blockIdx.x * 32;

    const float* qwh = qw + h*DH_*DH_;
    const float* kwh = kw + h*DH_*DH_;
    const float* vwh = vw + h*DH_*DH_;

    #pragma unroll
    for (int i = 0; i < 16; ++i) {
        int idx = t + i*256;
        int e = idx >> 6, d = idx & 63;
        wq[e][d] = qwh[idx];
        wk[e][d] = kwh[idx];
        wv[e][d] = vwh[idx];
    }
    #pragma unroll
    for (int i = 0; i < 8; ++i) {
        int idx = t + i*256;
        int r = idx >> 6, d = idx & 63;
        xs[r][d] = x[((size_t)(b*S_ + s0 + r))*D_ + h*DH_ + d];
    }
    __syncthreads();

    const int e  = t & 63;
    const int wg = t >> 6;
    float aq[8], ak[8], av[8];
    #pragma unroll
    for (int i = 0; i < 8; ++i) { aq[i] = 0.f; ak[i] = 0.f; av[i] = 0.f; }

    for (int d = 0; d < DH_; ++d) {
        float wqv = wq[e][d], wkv = wk[e][d], wvv = wv[e][d];
        #pragma unroll
        for (int i = 0; i < 8; ++i) {
            float xv = xs[wg*8 + i][d];
            aq[i] = fmaf(xv, wqv, aq[i]);
            ak[i] = fmaf(xv, wkv, ak[i]);
            av[i] = fmaf(xv, wvv, av[i]);
        }
    }

    const float qbe = qb[h*DH_ + e], kbe = kb[h*DH_ + e], vbe = vb[h*DH_ + e];
    v8s vv;
    #pragma unroll
    for (int i = 0; i < 8; ++i) {
        int s = s0 + wg*8 + i;
        size_t base = ((size_t)bh*S_ + s)*DH_ + e;
        Qo[base] = f2bf((aq[i] + qbe) * QSCL);
        Ko[base] = f2bf(ak[i] + kbe);
        vv[i]    = f2bf(av[i] + vbe);
    }
    // V^T store: lane e, 8 consecutive s -> one 16B store
    *(v8s*)(Vt + ((size_t)bh*DH_ + e)*S_ + s0 + wg*8) = vv;
}

// ---------------------------------------------------------------------------
// Kernel 2: flash attention, swapped QK^T, 32x32x16 MFMA.
// Per wave: 32 q rows. Per step: 64 kv. S^T/O^T layouts keep softmax lane-local.
// Fragment layouts (32x32x16, guide §3 m74/m101):
//   A: row=lane&31, k=(lane>>5)*8+j ; B: col=lane&31, k=(lane>>5)*8+j
//   C/D: col=lane&31, row=(reg&3)+8*(reg>>2)+4*(lane>>5)
// LDS tiles [64 rows][8 chunks of 16B], chunk slot = c ^ (row&7) (T2 swizzle).
// Writes unnormalized O^T partial + (m,l) per split; combine kernel merges.
// ---------------------------------------------------------------------------
__global__ __launch_bounds__(512, 1) void attn_kernel(
    const short* __restrict__ Q, const short* __restrict__ K,
    const short* __restrict__ Vt, float* __restrict__ Opart,
    float* __restrict__ Ml, int nspl, int kvlen)
{
    __shared__ __align__(16) short klds[2][64][64];
    __shared__ __align__(16) short vlds[2][64][64];

    const int t    = threadIdx.x;
    const int w    = t >> 6;
    const int l    = t & 63;
    const int l31  = l & 31;
    const int lhi  = l >> 5;
    const int bh   = blockIdx.y;
    const int qtil = blockIdx.x;
    const int spl  = blockIdx.z;
    const int q0   = qtil*QB + w*QW;
    const int kv_beg = spl * kvlen;

    const short* Qh = Q  + (size_t)bh*S_*DH_;
    const short* Kh = K  + (size_t)bh*S_*DH_;
    const short* Vh = Vt + (size_t)bh*DH_*S_;

    // staging: wave w stages rows w*8..w*8+7 of K-tile and V-tile.
    // dest chunk = l&7 at row w*8+(l>>3); source chunk pre-swizzled.
    const int rl  = l >> 3;
    const int cs  = (l & 7) ^ (rl & 7);
    const size_t koff = (size_t)(w*8 + rl)*DH_ + cs*8;
    const size_t voff = (size_t)(w*8 + rl)*S_  + cs*8;
    const int ldst = w*512 + l*8;   // linear dest (elements) within a buffer

    // Q B-frags (per-wave constant): q=q0+l31, dh = k0*16 + lhi*8 + j
    v8s qf[4];
    #pragma unroll
    for (int k0 = 0; k0 < 4; ++k0)
        qf[k0] = *(const v8s*)(Qh + (size_t)(q0 + l31)*DH_ + k0*16 + lhi*8);

    // swizzled frag-read offsets: fo[tile][chunkpair]
    int fo[2][4];
    #pragma unroll
    for (int a = 0; a < 2; ++a)
        #pragma unroll
        for (int c = 0; c < 4; ++c)
            fo[a][c] = (a*32 + l31)*64 + (((c*2 + lhi) ^ (l31 & 7))*8);

    v16f o0 = vz16(), o1 = vz16();
    float m_run = -INFINITY, l_run = 0.f;

    const int NT = kvlen / KVB;

    // prologue: stage tile 0 into buf 0
    {
        v8s k0v = *(const v8s*)(Kh + (size_t)kv_beg*DH_ + koff);
        v8s v0v = *(const v8s*)(Vh + kv_beg + voff);
        *(v8s*)((short*)klds[0] + ldst) = k0v;
        *(v8s*)((short*)vlds[0] + ldst) = v0v;
    }
    __syncthreads();

    for (int it = 0; it < NT; ++it) {
        const int cur = it & 1;

        // T14 async-split: issue next tile's global loads before compute
        v8s knx, vnx;
        if (it + 1 < NT) {
            size_t kvn = kv_beg + (size_t)(it+1)*KVB;
            knx = *(const v8s*)(Kh + kvn*DH_ + koff);
            vnx = *(const v8s*)(Vh + kvn + voff);
        }

        const short* kb = (const short*)klds[cur];
        const short* vb = (const short*)vlds[cur];

        // --- QK^T (swapped): S^T[kv][q], 2 kv-tiles of 32 ---
        v16f s0 = vz16(), s1 = vz16();
        #pragma unroll
        for (int k0 = 0; k0 < 4; ++k0) {
            v8s a0 = *(const v8s*)(kb + fo[0][k0]);
            v8s a1 = *(const v8s*)(kb + fo[1][k0]);
            s0 = __builtin_amdgcn_mfma_f32_32x32x16_bf16(a0, qf[k0], s0, 0, 0, 0);
            s1 = __builtin_amdgcn_mfma_f32_32x32x16_bf16(a1, qf[k0], s1, 0, 0, 0);
        }

        // --- online softmax (exp2 domain), lane-local + one xor-32 ---
        float mx = s0[0];
        #pragma unroll
        for (int i = 1; i < 16; ++i) mx = fmaxf(mx, s0[i]);
        #pragma unroll
        for (int i = 0; i < 16; ++i) mx = fmaxf(mx, s1[i]);
        mx = fmaxf(mx, __shfl_xor(mx, 32));
        float mn = fmaxf(m_run, mx);
        float sc = exp2f(m_run - mn);
        #pragma unroll
        for (int i = 0; i < 16; ++i) s0[i] = exp2f(s0[i] - mn);
        #pragma unroll
        for (int i = 0; i < 16; ++i) s1[i] = exp2f(s1[i] - mn);
        float ps = 0.f;
        #pragma unroll
        for (int i = 0; i < 16; ++i) ps += s0[i];
        #pragma unroll
        for (int i = 0; i < 16; ++i) ps += s1[i];
        ps += __shfl_xor(ps, 32);
        l_run = l_run * sc + ps;
        m_run = mn;
        #pragma unroll
        for (int i = 0; i < 16; ++i) { o0[i] *= sc; o1[i] *= sc; }

        // --- pack P -> 4 PV B-frags (cvt_pk + xor32 half-exchange) ---
        unsigned pw[4][4];
        #pragma unroll
        for (int kvt = 0; kvt < 2; ++kvt) {
            unsigned j[8];
            #pragma unroll
            for (int i = 0; i < 8; ++i)
                j[i] = kvt ? cvtpk(s1[2*i], s1[2*i+1]) : cvtpk(s0[2*i], s0[2*i+1]);
            #pragma unroll
            for (int hh = 0; hh < 2; ++hh) {
                unsigned x0 = j[hh*4+0], x1 = j[hh*4+1];
                unsigned y0 = j[hh*4+2], y1 = j[hh*4+3];
                unsigned sx0 = (unsigned)__shfl_xor((int)x0, 32);
                unsigned sx1 = (unsigned)__shfl_xor((int)x1, 32);
                unsigned sy0 = (unsigned)__shfl_xor((int)y0, 32);
                unsigned sy1 = (unsigned)__shfl_xor((int)y1, 32);
                bool lo = (l < 32);
                pw[kvt*2+hh][0] = lo ? x0  : sy0;
                pw[kvt*2+hh][1] = lo ? x1  : sy1;
                pw[kvt*2+hh][2] = lo ? sx0 : y0;
                pw[kvt*2+hh][3] = lo ? sx1 : y1;
            }
        }

        // --- PV: O^T[d][q] += V^T[d][kv] * P^T[kv][q] ---
        #pragma unroll
        for (int kk = 0; kk < 4; ++kk) {
            v4u u = { pw[kk][0], pw[kk][1], pw[kk][2], pw[kk][3] };
            v8s pf = __builtin_bit_cast(v8s, u);
            v8s va0 = *(const v8s*)(vb + fo[0][kk]);
            v8s va1 = *(const v8s*)(vb + fo[1][kk]);
            o0 = __builtin_amdgcn_mfma_f32_32x32x16_bf16(va0, pf, o0, 0, 0, 0);
            o1 = __builtin_amdgcn_mfma_f32_32x32x16_bf16(va1, pf, o1, 0, 0, 0);
        }

        // write next tile into other buffer (loads have had whole body to land)
        if (it + 1 < NT) {
            *(v8s*)((short*)klds[cur^1] + ldst) = knx;
            *(v8s*)((short*)vlds[cur^1] + ldst) = vnx;
        }
        __syncthreads();
    }

    // --- epilogue: dump unnormalized O^T (reg order) + m/l ---
    const int inst = bh*(S_/QW) + qtil*NW + w;
    float* od = Opart + ((size_t)inst*nspl + spl)*2048;
    #pragma unroll
    for (int r = 0; r < 16; ++r) od[r*64 + l]      = o0[r];
    #pragma unroll
    for (int r = 0; r < 16; ++r) od[(16+r)*64 + l] = o1[r];
    Ml[((size_t)inst*nspl + spl)*64 + l] = (l < 32) ? m_run : l_run;
}

// ---------------------------------------------------------------------------
// Kernel 3: merge KV-split partials, normalize, write fp32 out [B][S][D].
// One wave per q-instance; same (lane,reg)->(q,d) map as attn epilogue.
// ---------------------------------------------------------------------------
__global__ __launch_bounds__(256) void combine_kernel(
    const float* __restrict__ Opart, const float* __restrict__ Ml,
    float* __restrict__ out, int nspl)
{
    const int t = threadIdx.x;
    const int w = t >> 6, l = t & 63;
    const int inst = blockIdx.x*4 + w;
    const int bh = inst >> 7;           // / (S_/QW = 128)
    const int qw = inst & 127;
    const int b = bh >> 2, h = bh & 3;
    const int l31 = l & 31, lhi = l >> 5;
    const int q = qw*32 + l31;

    float m0, l0, m1 = -INFINITY, l1 = 0.f;
    {
        const float* mlp = Ml + (size_t)inst*nspl*64;
        m0 = mlp[l31]; l0 = mlp[32 + l31];
        if (nspl > 1) { m1 = mlp[64 + l31]; l1 = mlp[96 + l31]; }
    }
    float M  = fmaxf(m0, m1);
    float w0 = exp2f(m0 - M);
    float w1 = (nspl > 1) ? exp2f(m1 - M) : 0.f;
    float L  = l0*w0 + l1*w1;
    float inv = 1.f / L;

    const float* op0 = Opart + (size_t)inst*nspl*2048;
    float* outp = out + ((size_t)(b*S_ + q))*D_ + h*DH_;

    #pragma unroll
    for (int g = 0; g < 8; ++g) {
        v4f acc;
        #pragma unroll
        for (int jj = 0; jj < 4; ++jj) {
            int r = g*4 + jj;
            float v = op0[r*64 + l] * w0;
            if (nspl > 1) v += op0[2048 + r*64 + l] * w1;
            acc[jj] = v * inv;
        }
        int td = g >> 2, gg = g & 3;
        int d = td*32 + gg*8 + lhi*4;
        *(v4f*)(outp + d) = acc;
    }
}

extern "C" void kernel_launch(void* const* d_in, const int* in_sizes, int n_in,
                              void* d_out, int out_size, void* d_ws, size_t ws_size,
                              hipStream_t stream)
{
    const float* x  = (const float*)d_in[0];
    const float* qw = (const float*)d_in[1];
    const float* qb = (const float*)d_in[2];
    const float* kw = (const float*)d_in[3];
    const float* kb = (const float*)d_in[4];
    const float* vw = (const float*)d_in[5];
    const float* vb = (const float*)d_in[6];

    short* Qb  = (short*)d_ws;
    short* Kb  = Qb + NTOK;
    short* Vtb = Kb + NTOK;
    float* Opart = (float*)(Vtb + NTOK);            // 12,582,912 B offset

    // choose KV-split by workspace budget
    size_t base = (size_t)3*NTOK*sizeof(short);
    size_t per_spl = (size_t)NINST*2048*4 + (size_t)NINST*64*4;
    int nspl = (ws_size >= base + 2*per_spl) ? 2 : 1;
    float* Ml = Opart + (size_t)NINST*nspl*2048;
    int kvlen = S_/nspl;

    float* out = (float*)d_out;

    dim3 pg(S_/32, BH_), pb(256);
    hipLaunchKernelGGL(qkv_proj_kernel, pg, pb, 0, stream,
                       x, qw, qb, kw, kb, vw, vb, Qb, Kb, Vtb);

    dim3 ag(S_/QB, BH_, nspl), ab(512);
    hipLaunchKernelGGL(attn_kernel, ag, ab, 0, stream, Qb, Kb, Vtb, Opart, Ml, nspl, kvlen);

    dim3 cg(NINST/4), cb(256);
    hipLaunchKernelGGL(combine_kernel, cg, cb, 0, stream, Opart, Ml, out, nspl);
}

// Round 3
// 86.424 us; speedup vs baseline: 2.8967x; 1.2949x over previous
//
#include <hip/hip_runtime.h>
#include <hip/hip_bf16.h>

// MSA: B=2, S=4096, D=256, H=4, DH=64. fp32 in/out, bf16 MFMA internally.
// R3: + nspl=4 KV-split (occupancy 2 blocks/CU), defer-max (T13), tree
//     reductions, permlane32_swap pack (T12), setprio around MFMA (T5).

#define B_   2
#define S_   4096
#define D_   256
#define H_   4
#define DH_  64
#define BH_  8
#define NTOK (BH_*S_*DH_)   // elements per Q/K/V buffer

#define KVB  64             // kv tile per step
#define QW   32             // q rows per wave
#define NW   8              // waves per block
#define QB   (QW*NW)        // 256 q rows per block
#define NINST (BH_*(S_/QW)) // 1024 q-wave instances

typedef short v8s __attribute__((ext_vector_type(8)));
typedef float v16f __attribute__((ext_vector_type(16)));
typedef float v4f __attribute__((ext_vector_type(4)));
typedef unsigned v4u __attribute__((ext_vector_type(4)));
typedef int v2i __attribute__((ext_vector_type(2)));

#define QSCL (0.125f * 1.4426950408889634f)   // 1/sqrt(64) * log2(e): exp2 domain
#define DEFER_THR 8.0f                        // T13: P bounded by 2^8

static __device__ __forceinline__ short f2bf(float f) {
    __hip_bfloat16 h = __float2bfloat16(f);
    return *reinterpret_cast<short*>(&h);
}
static __device__ __forceinline__ unsigned cvtpk(float lo, float hi) {
    unsigned r;
    asm("v_cvt_pk_bf16_f32 %0, %1, %2" : "=v"(r) : "v"(lo), "v"(hi));
    return r;
}
// Swap upper half of a with lower half of b (v_permlane32_swap_b32).
static __device__ __forceinline__ void pl32swap(unsigned &a, unsigned &b) {
#if __has_builtin(__builtin_amdgcn_permlane32_swap)
    v2i r = __builtin_amdgcn_permlane32_swap((int)a, (int)b, false, false);
    a = (unsigned)r[0]; b = (unsigned)r[1];
#else
    asm volatile("v_permlane32_swap_b32 %0, %1" : "+v"(a), "+v"(b));
#endif
}
static __device__ __forceinline__ v16f vz16() {
    v16f z;
    #pragma unroll
    for (int i = 0; i < 16; ++i) z[i] = 0.f;
    return z;
}

// ---------------------------------------------------------------------------
// Kernel 1: fused QKV projection (fp32 compute) -> bf16.
//   Q: [BH][S][DH] pre-scaled by QSCL; K: [BH][S][DH]; Vt: [BH][DH][S].
// ---------------------------------------------------------------------------
__global__ __launch_bounds__(256) void qkv_proj_kernel(
    const float* __restrict__ x,
    const float* __restrict__ qw, const float* __restrict__ qb,
    const float* __restrict__ kw, const float* __restrict__ kb,
    const float* __restrict__ vw, const float* __restrict__ vb,
    short* __restrict__ Qo, short* __restrict__ Ko, short* __restrict__ Vt)
{
    __shared__ float wq[DH_][DH_+1];
    __shared__ float wk[DH_][DH_+1];
    __shared__ float wv[DH_][DH_+1];
    __shared__ float xs[32][DH_];

    const int t  = threadIdx.x;
    const int bh = blockIdx.y;
    const int h  = bh & (H_-1);
    const int b  = bh >> 2;
    const int s0 = blockIdx.x * 32;

    const float* qwh = qw + h*DH_*DH_;
    const float* kwh = kw + h*DH_*DH_;
    const float* vwh = vw + h*DH_*DH_;

    #pragma unroll
    for (int i = 0; i < 16; ++i) {
        int idx = t + i*256;
        int e = idx >> 6, d = idx & 63;
        wq[e][d] = qwh[idx];
        wk[e][d] = kwh[idx];
        wv[e][d] = vwh[idx];
    }
    #pragma unroll
    for (int i = 0; i < 8; ++i) {
        int idx = t + i*256;
        int r = idx >> 6, d = idx & 63;
        xs[r][d] = x[((size_t)(b*S_ + s0 + r))*D_ + h*DH_ + d];
    }
    __syncthreads();

    const int e  = t & 63;
    const int wg = t >> 6;
    float aq[8], ak[8], av[8];
    #pragma unroll
    for (int i = 0; i < 8; ++i) { aq[i] = 0.f; ak[i] = 0.f; av[i] = 0.f; }

    for (int d = 0; d < DH_; ++d) {
        float wqv = wq[e][d], wkv = wk[e][d], wvv = wv[e][d];
        #pragma unroll
        for (int i = 0; i < 8; ++i) {
            float xv = xs[wg*8 + i][d];
            aq[i] = fmaf(xv, wqv, aq[i]);
            ak[i] = fmaf(xv, wkv, ak[i]);
            av[i] = fmaf(xv, wvv, av[i]);
        }
    }

    const float qbe = qb[h*DH_ + e], kbe = kb[h*DH_ + e], vbe = vb[h*DH_ + e];
    v8s vv;
    #pragma unroll
    for (int i = 0; i < 8; ++i) {
        int s = s0 + wg*8 + i;
        size_t base = ((size_t)bh*S_ + s)*DH_ + e;
        Qo[base] = f2bf((aq[i] + qbe) * QSCL);
        Ko[base] = f2bf(ak[i] + kbe);
        vv[i]    = f2bf(av[i] + vbe);
    }
    // V^T store: lane e, 8 consecutive s -> one 16B store
    *(v8s*)(Vt + ((size_t)bh*DH_ + e)*S_ + s0 + wg*8) = vv;
}

// ---------------------------------------------------------------------------
// Kernel 2: flash attention, swapped QK^T, 32x32x16 MFMA.
// Fragment layouts (32x32x16, m74/m101):
//   A: row=lane&31, k=(lane>>5)*8+j ; B: col=lane&31, k=(lane>>5)*8+j
//   C/D: col=lane&31, row=(reg&3)+8*(reg>>2)+4*(lane>>5)
// LDS tiles [64 rows][8 chunks of 16B], chunk slot = c ^ (row&7) (T2 swizzle,
// applied via pre-swizzled global source + swizzled reads).
// ---------------------------------------------------------------------------
__global__ __launch_bounds__(512, 4) void attn_kernel(
    const short* __restrict__ Q, const short* __restrict__ K,
    const short* __restrict__ Vt, float* __restrict__ Opart,
    float* __restrict__ Ml, int nspl, int kvlen)
{
    __shared__ __align__(16) short klds[2][64][64];
    __shared__ __align__(16) short vlds[2][64][64];

    const int t    = threadIdx.x;
    const int w    = t >> 6;
    const int l    = t & 63;
    const int l31  = l & 31;
    const int lhi  = l >> 5;
    const int bh   = blockIdx.y;
    const int qtil = blockIdx.x;
    const int spl  = blockIdx.z;
    const int q0   = qtil*QB + w*QW;
    const int kv_beg = spl * kvlen;

    const short* Qh = Q  + (size_t)bh*S_*DH_;
    const short* Kh = K  + (size_t)bh*S_*DH_;
    const short* Vh = Vt + (size_t)bh*DH_*S_;

    // staging: wave w stages rows w*8..w*8+7; source chunk pre-swizzled (T2)
    const int rl  = l >> 3;
    const int cs  = (l & 7) ^ (rl & 7);
    const size_t koff = (size_t)(w*8 + rl)*DH_ + cs*8;
    const size_t voff = (size_t)(w*8 + rl)*S_  + cs*8;
    const int ldst = w*512 + l*8;

    // Q B-frags (per-wave constant): q=q0+l31, dh = k0*16 + lhi*8 + j
    v8s qf[4];
    #pragma unroll
    for (int k0 = 0; k0 < 4; ++k0)
        qf[k0] = *(const v8s*)(Qh + (size_t)(q0 + l31)*DH_ + k0*16 + lhi*8);

    // swizzled frag-read offsets: fo[tile][chunkpair]
    int fo[2][4];
    #pragma unroll
    for (int a = 0; a < 2; ++a)
        #pragma unroll
        for (int c = 0; c < 4; ++c)
            fo[a][c] = (a*32 + l31)*64 + (((c*2 + lhi) ^ (l31 & 7))*8);

    v16f o0 = vz16(), o1 = vz16();
    float m_run = -INFINITY, l_run = 0.f;

    const int NT = kvlen / KVB;

    // prologue: stage tile 0 into buf 0
    {
        v8s k0v = *(const v8s*)(Kh + (size_t)kv_beg*DH_ + koff);
        v8s v0v = *(const v8s*)(Vh + kv_beg + voff);
        *(v8s*)((short*)klds[0] + ldst) = k0v;
        *(v8s*)((short*)vlds[0] + ldst) = v0v;
    }
    __syncthreads();

    for (int it = 0; it < NT; ++it) {
        const int cur = it & 1;

        // T14 async-split: issue next tile's global loads before compute
        v8s knx, vnx;
        if (it + 1 < NT) {
            size_t kvn = kv_beg + (size_t)(it+1)*KVB;
            knx = *(const v8s*)(Kh + kvn*DH_ + koff);
            vnx = *(const v8s*)(Vh + kvn + voff);
        }

        const short* kb = (const short*)klds[cur];
        const short* vb = (const short*)vlds[cur];

        // --- QK^T (swapped): S^T[kv][q], 2 kv-tiles of 32 ---
        v16f s0 = vz16(), s1 = vz16();
        __builtin_amdgcn_s_setprio(1);
        #pragma unroll
        for (int k0 = 0; k0 < 4; ++k0) {
            v8s a0 = *(const v8s*)(kb + fo[0][k0]);
            v8s a1 = *(const v8s*)(kb + fo[1][k0]);
            s0 = __builtin_amdgcn_mfma_f32_32x32x16_bf16(a0, qf[k0], s0, 0, 0, 0);
            s1 = __builtin_amdgcn_mfma_f32_32x32x16_bf16(a1, qf[k0], s1, 0, 0, 0);
        }
        __builtin_amdgcn_s_setprio(0);

        // --- online softmax (exp2 domain), tree reductions + defer-max ---
        float t16[16];
        #pragma unroll
        for (int i = 0; i < 16; ++i) t16[i] = fmaxf(s0[i], s1[i]);
        #pragma unroll
        for (int st = 8; st; st >>= 1)
            #pragma unroll
            for (int i = 0; i < st; ++i) t16[i] = fmaxf(t16[i], t16[i+st]);
        float mx = fmaxf(t16[0], __shfl_xor(t16[0], 32));

        if (__any(mx > m_run + DEFER_THR)) {     // T13: rarely taken after tile 0
            float mn = fmaxf(m_run, mx);
            float sc = exp2f(m_run - mn);
            #pragma unroll
            for (int i = 0; i < 16; ++i) { o0[i] *= sc; o1[i] *= sc; }
            l_run *= sc;
            m_run = mn;
        }
        #pragma unroll
        for (int i = 0; i < 16; ++i) s0[i] = exp2f(s0[i] - m_run);
        #pragma unroll
        for (int i = 0; i < 16; ++i) s1[i] = exp2f(s1[i] - m_run);
        float a16[16];
        #pragma unroll
        for (int i = 0; i < 16; ++i) a16[i] = s0[i] + s1[i];
        #pragma unroll
        for (int st = 8; st; st >>= 1)
            #pragma unroll
            for (int i = 0; i < st; ++i) a16[i] += a16[i+st];
        l_run += a16[0] + __shfl_xor(a16[0], 32);

        // --- pack P -> 4 PV B-frags (T12: cvt_pk + permlane32_swap) ---
        unsigned pwv[4][4];
        {
            unsigned j0 = cvtpk(s0[0], s0[1]),  j1 = cvtpk(s0[2], s0[3]);
            unsigned j2 = cvtpk(s0[4], s0[5]),  j3 = cvtpk(s0[6], s0[7]);
            unsigned j4 = cvtpk(s0[8], s0[9]),  j5 = cvtpk(s0[10], s0[11]);
            unsigned j6 = cvtpk(s0[12], s0[13]), j7 = cvtpk(s0[14], s0[15]);
            pl32swap(j0, j2); pl32swap(j1, j3);
            pwv[0][0] = j0; pwv[0][1] = j1; pwv[0][2] = j2; pwv[0][3] = j3;
            pl32swap(j4, j6); pl32swap(j5, j7);
            pwv[1][0] = j4; pwv[1][1] = j5; pwv[1][2] = j6; pwv[1][3] = j7;
        }
        {
            unsigned j0 = cvtpk(s1[0], s1[1]),  j1 = cvtpk(s1[2], s1[3]);
            unsigned j2 = cvtpk(s1[4], s1[5]),  j3 = cvtpk(s1[6], s1[7]);
            unsigned j4 = cvtpk(s1[8], s1[9]),  j5 = cvtpk(s1[10], s1[11]);
            unsigned j6 = cvtpk(s1[12], s1[13]), j7 = cvtpk(s1[14], s1[15]);
            pl32swap(j0, j2); pl32swap(j1, j3);
            pwv[2][0] = j0; pwv[2][1] = j1; pwv[2][2] = j2; pwv[2][3] = j3;
            pl32swap(j4, j6); pl32swap(j5, j7);
            pwv[3][0] = j4; pwv[3][1] = j5; pwv[3][2] = j6; pwv[3][3] = j7;
        }

        // --- PV: O^T[d][q] += V^T[d][kv] * P^T[kv][q] ---
        __builtin_amdgcn_s_setprio(1);
        #pragma unroll
        for (int kk = 0; kk < 4; ++kk) {
            v4u u = { pwv[kk][0], pwv[kk][1], pwv[kk][2], pwv[kk][3] };
            v8s pf = __builtin_bit_cast(v8s, u);
            v8s va0 = *(const v8s*)(vb + fo[0][kk]);
            v8s va1 = *(const v8s*)(vb + fo[1][kk]);
            o0 = __builtin_amdgcn_mfma_f32_32x32x16_bf16(va0, pf, o0, 0, 0, 0);
            o1 = __builtin_amdgcn_mfma_f32_32x32x16_bf16(va1, pf, o1, 0, 0, 0);
        }
        __builtin_amdgcn_s_setprio(0);

        // stage next tile into other buffer (loads had whole body to land)
        if (it + 1 < NT) {
            *(v8s*)((short*)klds[cur^1] + ldst) = knx;
            *(v8s*)((short*)vlds[cur^1] + ldst) = vnx;
        }
        __syncthreads();
    }

    // --- epilogue: dump unnormalized O^T (reg order) + m/l ---
    const int inst = bh*(S_/QW) + qtil*NW + w;
    float* od = Opart + ((size_t)inst*nspl + spl)*2048;
    #pragma unroll
    for (int r = 0; r < 16; ++r) od[r*64 + l]      = o0[r];
    #pragma unroll
    for (int r = 0; r < 16; ++r) od[(16+r)*64 + l] = o1[r];
    Ml[((size_t)inst*nspl + spl)*64 + l] = (l < 32) ? m_run : l_run;
}

// ---------------------------------------------------------------------------
// Kernel 3: merge KV-split partials, normalize, write fp32 out [B][S][D].
// Templated on NSPL so all arrays are compile-time indexed (rule #20).
// ---------------------------------------------------------------------------
template<int NSPL>
__global__ __launch_bounds__(256) void combine_kernel(
    const float* __restrict__ Opart, const float* __restrict__ Ml,
    float* __restrict__ out)
{
    const int t = threadIdx.x;
    const int w = t >> 6, l = t & 63;
    const int inst = blockIdx.x*4 + w;
    const int bh = inst >> 7;           // / (S_/QW = 128)
    const int qw = inst & 127;
    const int b = bh >> 2, h = bh & 3;
    const int l31 = l & 31, lhi = l >> 5;
    const int q = qw*32 + l31;

    const float* mlp = Ml + (size_t)inst*NSPL*64;
    float m[NSPL], lv[NSPL];
    float M = -INFINITY;
    #pragma unroll
    for (int sp = 0; sp < NSPL; ++sp) {
        m[sp]  = mlp[sp*64 + l31];
        lv[sp] = mlp[sp*64 + 32 + l31];
        M = fmaxf(M, m[sp]);
    }
    float wgt[NSPL], L = 0.f;
    #pragma unroll
    for (int sp = 0; sp < NSPL; ++sp) {
        wgt[sp] = exp2f(m[sp] - M);
        L += lv[sp] * wgt[sp];
    }
    float inv = 1.f / L;

    const float* op0 = Opart + (size_t)inst*NSPL*2048;
    float* outp = out + ((size_t)(b*S_ + q))*D_ + h*DH_;

    #pragma unroll
    for (int g = 0; g < 8; ++g) {
        v4f acc;
        #pragma unroll
        for (int jj = 0; jj < 4; ++jj) {
            int r = g*4 + jj;
            float v = 0.f;
            #pragma unroll
            for (int sp = 0; sp < NSPL; ++sp)
                v += op0[sp*2048 + r*64 + l] * wgt[sp];
            acc[jj] = v * inv;
        }
        int td = g >> 2, gg = g & 3;
        int d = td*32 + gg*8 + lhi*4;
        *(v4f*)(outp + d) = acc;
    }
}

extern "C" void kernel_launch(void* const* d_in, const int* in_sizes, int n_in,
                              void* d_out, int out_size, void* d_ws, size_t ws_size,
                              hipStream_t stream)
{
    const float* x  = (const float*)d_in[0];
    const float* qw = (const float*)d_in[1];
    const float* qb = (const float*)d_in[2];
    const float* kw = (const float*)d_in[3];
    const float* kb = (const float*)d_in[4];
    const float* vw = (const float*)d_in[5];
    const float* vb = (const float*)d_in[6];

    short* Qb  = (short*)d_ws;
    short* Kb  = Qb + NTOK;
    short* Vtb = Kb + NTOK;
    float* Opart = (float*)(Vtb + NTOK);

    // choose KV-split by workspace budget (prefer 4: 2 blocks/CU)
    size_t base = (size_t)3*NTOK*sizeof(short);
    size_t per_spl = (size_t)NINST*2048*4 + (size_t)NINST*64*4;
    int nspl = 1;
    if      (ws_size >= base + 4*per_spl) nspl = 4;
    else if (ws_size >= base + 2*per_spl) nspl = 2;
    float* Ml = Opart + (size_t)NINST*nspl*2048;
    int kvlen = S_/nspl;

    float* out = (float*)d_out;

    dim3 pg(S_/32, BH_), pb(256);
    hipLaunchKernelGGL(qkv_proj_kernel, pg, pb, 0, stream,
                       x, qw, qb, kw, kb, vw, vb, Qb, Kb, Vtb);

    dim3 ag(S_/QB, BH_, nspl), ab(512);
    hipLaunchKernelGGL(attn_kernel, ag, ab, 0, stream, Qb, Kb, Vtb, Opart, Ml, nspl, kvlen);

    dim3 cg(NINST/4), cb(256);
    if (nspl == 4)
        hipLaunchKernelGGL(combine_kernel<4>, cg, cb, 0, stream, Opart, Ml, out);
    else if (nspl == 2)
        hipLaunchKernelGGL(combine_kernel<2>, cg, cb, 0, stream, Opart, Ml, out);
    else
        hipLaunchKernelGGL(combine_kernel<1>, cg, cb, 0, stream, Opart, Ml, out);
}

// Round 4
// 76.217 us; speedup vs baseline: 3.2846x; 1.1339x over previous
//
#include <hip/hip_runtime.h>
#include <hip/hip_bf16.h>

// MSA: B=2, S=4096, D=256, H=4, DH=64. fp32 in/out, bf16 MFMA internally.
// R4: raw v_exp_f32 (skip ocml wrapper), v_max3 reduction tree.
//     Structure from R3: swapped-QK^T 32x32, nspl=4 KV-split, T2 swizzle,
//     T12 permlane pack, T13 defer-max, T14 async staging, T5 setprio.

#define B_   2
#define S_   4096
#define D_   256
#define H_   4
#define DH_  64
#define BH_  8
#define NTOK (BH_*S_*DH_)   // elements per Q/K/V buffer

#define KVB  64             // kv tile per step
#define QW   32             // q rows per wave
#define NW   8              // waves per block
#define QB   (QW*NW)        // 256 q rows per block
#define NINST (BH_*(S_/QW)) // 1024 q-wave instances

typedef short v8s __attribute__((ext_vector_type(8)));
typedef float v16f __attribute__((ext_vector_type(16)));
typedef float v4f __attribute__((ext_vector_type(4)));
typedef unsigned v4u __attribute__((ext_vector_type(4)));
typedef int v2i __attribute__((ext_vector_type(2)));

#define QSCL (0.125f * 1.4426950408889634f)   // 1/sqrt(64) * log2(e): exp2 domain
#define DEFER_THR 8.0f                        // T13: P bounded by 2^8

static __device__ __forceinline__ short f2bf(float f) {
    __hip_bfloat16 h = __float2bfloat16(f);
    return *reinterpret_cast<short*>(&h);
}
static __device__ __forceinline__ unsigned cvtpk(float lo, float hi) {
    unsigned r;
    asm("v_cvt_pk_bf16_f32 %0, %1, %2" : "=v"(r) : "v"(lo), "v"(hi));
    return r;
}
// Raw v_exp_f32: args are <=0 finite; denormal flush acceptable here.
static __device__ __forceinline__ float fexp2(float x) {
#if __has_builtin(__builtin_amdgcn_exp2f)
    return __builtin_amdgcn_exp2f(x);
#else
    float r;
    asm("v_exp_f32 %0, %1" : "=v"(r) : "v"(x));
    return r;
#endif
}
static __device__ __forceinline__ float max3f(float a, float b, float c) {
    return fmaxf(fmaxf(a, b), c);   // clang fuses to v_max3_f32
}
// Swap upper half of a with lower half of b (v_permlane32_swap_b32).
static __device__ __forceinline__ void pl32swap(unsigned &a, unsigned &b) {
#if __has_builtin(__builtin_amdgcn_permlane32_swap)
    v2i r = __builtin_amdgcn_permlane32_swap((int)a, (int)b, false, false);
    a = (unsigned)r[0]; b = (unsigned)r[1];
#else
    asm volatile("v_permlane32_swap_b32 %0, %1" : "+v"(a), "+v"(b));
#endif
}
static __device__ __forceinline__ v16f vz16() {
    v16f z;
    #pragma unroll
    for (int i = 0; i < 16; ++i) z[i] = 0.f;
    return z;
}

// ---------------------------------------------------------------------------
// Kernel 1: fused QKV projection (fp32 compute) -> bf16.
//   Q: [BH][S][DH] pre-scaled by QSCL; K: [BH][S][DH]; Vt: [BH][DH][S].
// ---------------------------------------------------------------------------
__global__ __launch_bounds__(256) void qkv_proj_kernel(
    const float* __restrict__ x,
    const float* __restrict__ qw, const float* __restrict__ qb,
    const float* __restrict__ kw, const float* __restrict__ kb,
    const float* __restrict__ vw, const float* __restrict__ vb,
    short* __restrict__ Qo, short* __restrict__ Ko, short* __restrict__ Vt)
{
    __shared__ float wq[DH_][DH_+1];
    __shared__ float wk[DH_][DH_+1];
    __shared__ float wv[DH_][DH_+1];
    __shared__ float xs[32][DH_];

    const int t  = threadIdx.x;
    const int bh = blockIdx.y;
    const int h  = bh & (H_-1);
    const int b  = bh >> 2;
    const int s0 = blockIdx.x * 32;

    const float* qwh = qw + h*DH_*DH_;
    const float* kwh = kw + h*DH_*DH_;
    const float* vwh = vw + h*DH_*DH_;

    #pragma unroll
    for (int i = 0; i < 16; ++i) {
        int idx = t + i*256;
        int e = idx >> 6, d = idx & 63;
        wq[e][d] = qwh[idx];
        wk[e][d] = kwh[idx];
        wv[e][d] = vwh[idx];
    }
    #pragma unroll
    for (int i = 0; i < 8; ++i) {
        int idx = t + i*256;
        int r = idx >> 6, d = idx & 63;
        xs[r][d] = x[((size_t)(b*S_ + s0 + r))*D_ + h*DH_ + d];
    }
    __syncthreads();

    const int e  = t & 63;
    const int wg = t >> 6;
    float aq[8], ak[8], av[8];
    #pragma unroll
    for (int i = 0; i < 8; ++i) { aq[i] = 0.f; ak[i] = 0.f; av[i] = 0.f; }

    for (int d = 0; d < DH_; ++d) {
        float wqv = wq[e][d], wkv = wk[e][d], wvv = wv[e][d];
        #pragma unroll
        for (int i = 0; i < 8; ++i) {
            float xv = xs[wg*8 + i][d];
            aq[i] = fmaf(xv, wqv, aq[i]);
            ak[i] = fmaf(xv, wkv, ak[i]);
            av[i] = fmaf(xv, wvv, av[i]);
        }
    }

    const float qbe = qb[h*DH_ + e], kbe = kb[h*DH_ + e], vbe = vb[h*DH_ + e];
    v8s vv;
    #pragma unroll
    for (int i = 0; i < 8; ++i) {
        int s = s0 + wg*8 + i;
        size_t base = ((size_t)bh*S_ + s)*DH_ + e;
        Qo[base] = f2bf((aq[i] + qbe) * QSCL);
        Ko[base] = f2bf(ak[i] + kbe);
        vv[i]    = f2bf(av[i] + vbe);
    }
    // V^T store: lane e, 8 consecutive s -> one 16B store
    *(v8s*)(Vt + ((size_t)bh*DH_ + e)*S_ + s0 + wg*8) = vv;
}

// ---------------------------------------------------------------------------
// Kernel 2: flash attention, swapped QK^T, 32x32x16 MFMA.
// Fragment layouts (32x32x16, m74/m101):
//   A: row=lane&31, k=(lane>>5)*8+j ; B: col=lane&31, k=(lane>>5)*8+j
//   C/D: col=lane&31, row=(reg&3)+8*(reg>>2)+4*(lane>>5)
// LDS tiles [64 rows][8 chunks of 16B], chunk slot = c ^ (row&7) (T2 swizzle,
// applied via pre-swizzled global source + swizzled reads).
// ---------------------------------------------------------------------------
__global__ __launch_bounds__(512, 4) void attn_kernel(
    const short* __restrict__ Q, const short* __restrict__ K,
    const short* __restrict__ Vt, float* __restrict__ Opart,
    float* __restrict__ Ml, int nspl, int kvlen)
{
    __shared__ __align__(16) short klds[2][64][64];
    __shared__ __align__(16) short vlds[2][64][64];

    const int t    = threadIdx.x;
    const int w    = t >> 6;
    const int l    = t & 63;
    const int l31  = l & 31;
    const int lhi  = l >> 5;
    const int bh   = blockIdx.y;
    const int qtil = blockIdx.x;
    const int spl  = blockIdx.z;
    const int q0   = qtil*QB + w*QW;
    const int kv_beg = spl * kvlen;

    const short* Qh = Q  + (size_t)bh*S_*DH_;
    const short* Kh = K  + (size_t)bh*S_*DH_;
    const short* Vh = Vt + (size_t)bh*DH_*S_;

    // staging: wave w stages rows w*8..w*8+7; source chunk pre-swizzled (T2)
    const int rl  = l >> 3;
    const int cs  = (l & 7) ^ (rl & 7);
    const size_t koff = (size_t)(w*8 + rl)*DH_ + cs*8;
    const size_t voff = (size_t)(w*8 + rl)*S_  + cs*8;
    const int ldst = w*512 + l*8;

    // Q B-frags (per-wave constant): q=q0+l31, dh = k0*16 + lhi*8 + j
    v8s qf[4];
    #pragma unroll
    for (int k0 = 0; k0 < 4; ++k0)
        qf[k0] = *(const v8s*)(Qh + (size_t)(q0 + l31)*DH_ + k0*16 + lhi*8);

    // swizzled frag-read offsets: fo[tile][chunkpair]
    int fo[2][4];
    #pragma unroll
    for (int a = 0; a < 2; ++a)
        #pragma unroll
        for (int c = 0; c < 4; ++c)
            fo[a][c] = (a*32 + l31)*64 + (((c*2 + lhi) ^ (l31 & 7))*8);

    v16f o0 = vz16(), o1 = vz16();
    float m_run = -INFINITY, l_run = 0.f;

    const int NT = kvlen / KVB;

    // prologue: stage tile 0 into buf 0
    {
        v8s k0v = *(const v8s*)(Kh + (size_t)kv_beg*DH_ + koff);
        v8s v0v = *(const v8s*)(Vh + kv_beg + voff);
        *(v8s*)((short*)klds[0] + ldst) = k0v;
        *(v8s*)((short*)vlds[0] + ldst) = v0v;
    }
    __syncthreads();

    for (int it = 0; it < NT; ++it) {
        const int cur = it & 1;

        // T14 async-split: issue next tile's global loads before compute
        v8s knx, vnx;
        if (it + 1 < NT) {
            size_t kvn = kv_beg + (size_t)(it+1)*KVB;
            knx = *(const v8s*)(Kh + kvn*DH_ + koff);
            vnx = *(const v8s*)(Vh + kvn + voff);
        }

        const short* kb = (const short*)klds[cur];
        const short* vb = (const short*)vlds[cur];

        // --- QK^T (swapped): S^T[kv][q], 2 kv-tiles of 32 ---
        v16f s0 = vz16(), s1 = vz16();
        __builtin_amdgcn_s_setprio(1);
        #pragma unroll
        for (int k0 = 0; k0 < 4; ++k0) {
            v8s a0 = *(const v8s*)(kb + fo[0][k0]);
            v8s a1 = *(const v8s*)(kb + fo[1][k0]);
            s0 = __builtin_amdgcn_mfma_f32_32x32x16_bf16(a0, qf[k0], s0, 0, 0, 0);
            s1 = __builtin_amdgcn_mfma_f32_32x32x16_bf16(a1, qf[k0], s1, 0, 0, 0);
        }
        __builtin_amdgcn_s_setprio(0);

        // --- online softmax (exp2 domain), max3 tree + defer-max ---
        float t16[16];
        #pragma unroll
        for (int i = 0; i < 16; ++i) t16[i] = fmaxf(s0[i], s1[i]);
        // 16 -> 6 -> 2 -> 1 via v_max3
        float r0 = max3f(t16[0],  t16[1],  t16[2]);
        float r1 = max3f(t16[3],  t16[4],  t16[5]);
        float r2 = max3f(t16[6],  t16[7],  t16[8]);
        float r3 = max3f(t16[9],  t16[10], t16[11]);
        float r4 = max3f(t16[12], t16[13], t16[14]);
        float mx = fmaxf(max3f(max3f(r0, r1, r2), r3, r4), t16[15]);
        mx = fmaxf(mx, __shfl_xor(mx, 32));

        if (__any(mx > m_run + DEFER_THR)) {     // T13: rarely taken after tile 0
            float mn = fmaxf(m_run, mx);
            float sc = fexp2(m_run - mn);
            #pragma unroll
            for (int i = 0; i < 16; ++i) { o0[i] *= sc; o1[i] *= sc; }
            l_run *= sc;
            m_run = mn;
        }
        #pragma unroll
        for (int i = 0; i < 16; ++i) s0[i] = fexp2(s0[i] - m_run);
        #pragma unroll
        for (int i = 0; i < 16; ++i) s1[i] = fexp2(s1[i] - m_run);
        float a16[16];
        #pragma unroll
        for (int i = 0; i < 16; ++i) a16[i] = s0[i] + s1[i];
        #pragma unroll
        for (int st = 8; st; st >>= 1)
            #pragma unroll
            for (int i = 0; i < st; ++i) a16[i] += a16[i+st];
        l_run += a16[0] + __shfl_xor(a16[0], 32);

        // --- pack P -> 4 PV B-frags (T12: cvt_pk + permlane32_swap) ---
        unsigned pwv[4][4];
        {
            unsigned j0 = cvtpk(s0[0], s0[1]),  j1 = cvtpk(s0[2], s0[3]);
            unsigned j2 = cvtpk(s0[4], s0[5]),  j3 = cvtpk(s0[6], s0[7]);
            unsigned j4 = cvtpk(s0[8], s0[9]),  j5 = cvtpk(s0[10], s0[11]);
            unsigned j6 = cvtpk(s0[12], s0[13]), j7 = cvtpk(s0[14], s0[15]);
            pl32swap(j0, j2); pl32swap(j1, j3);
            pwv[0][0] = j0; pwv[0][1] = j1; pwv[0][2] = j2; pwv[0][3] = j3;
            pl32swap(j4, j6); pl32swap(j5, j7);
            pwv[1][0] = j4; pwv[1][1] = j5; pwv[1][2] = j6; pwv[1][3] = j7;
        }
        {
            unsigned j0 = cvtpk(s1[0], s1[1]),  j1 = cvtpk(s1[2], s1[3]);
            unsigned j2 = cvtpk(s1[4], s1[5]),  j3 = cvtpk(s1[6], s1[7]);
            unsigned j4 = cvtpk(s1[8], s1[9]),  j5 = cvtpk(s1[10], s1[11]);
            unsigned j6 = cvtpk(s1[12], s1[13]), j7 = cvtpk(s1[14], s1[15]);
            pl32swap(j0, j2); pl32swap(j1, j3);
            pwv[2][0] = j0; pwv[2][1] = j1; pwv[2][2] = j2; pwv[2][3] = j3;
            pl32swap(j4, j6); pl32swap(j5, j7);
            pwv[3][0] = j4; pwv[3][1] = j5; pwv[3][2] = j6; pwv[3][3] = j7;
        }

        // --- PV: O^T[d][q] += V^T[d][kv] * P^T[kv][q] ---
        __builtin_amdgcn_s_setprio(1);
        #pragma unroll
        for (int kk = 0; kk < 4; ++kk) {
            v4u u = { pwv[kk][0], pwv[kk][1], pwv[kk][2], pwv[kk][3] };
            v8s pf = __builtin_bit_cast(v8s, u);
            v8s va0 = *(const v8s*)(vb + fo[0][kk]);
            v8s va1 = *(const v8s*)(vb + fo[1][kk]);
            o0 = __builtin_amdgcn_mfma_f32_32x32x16_bf16(va0, pf, o0, 0, 0, 0);
            o1 = __builtin_amdgcn_mfma_f32_32x32x16_bf16(va1, pf, o1, 0, 0, 0);
        }
        __builtin_amdgcn_s_setprio(0);

        // stage next tile into other buffer (loads had whole body to land)
        if (it + 1 < NT) {
            *(v8s*)((short*)klds[cur^1] + ldst) = knx;
            *(v8s*)((short*)vlds[cur^1] + ldst) = vnx;
        }
        __syncthreads();
    }

    // --- epilogue: dump unnormalized O^T (reg order) + m/l ---
    const int inst = bh*(S_/QW) + qtil*NW + w;
    float* od = Opart + ((size_t)inst*nspl + spl)*2048;
    #pragma unroll
    for (int r = 0; r < 16; ++r) od[r*64 + l]      = o0[r];
    #pragma unroll
    for (int r = 0; r < 16; ++r) od[(16+r)*64 + l] = o1[r];
    Ml[((size_t)inst*nspl + spl)*64 + l] = (l < 32) ? m_run : l_run;
}

// ---------------------------------------------------------------------------
// Kernel 3: merge KV-split partials, normalize, write fp32 out [B][S][D].
// ---------------------------------------------------------------------------
template<int NSPL>
__global__ __launch_bounds__(256) void combine_kernel(
    const float* __restrict__ Opart, const float* __restrict__ Ml,
    float* __restrict__ out)
{
    const int t = threadIdx.x;
    const int w = t >> 6, l = t & 63;
    const int inst = blockIdx.x*4 + w;
    const int bh = inst >> 7;           // / (S_/QW = 128)
    const int qw = inst & 127;
    const int b = bh >> 2, h = bh & 3;
    const int l31 = l & 31, lhi = l >> 5;
    const int q = qw*32 + l31;

    const float* mlp = Ml + (size_t)inst*NSPL*64;
    float m[NSPL], lv[NSPL];
    float M = -INFINITY;
    #pragma unroll
    for (int sp = 0; sp < NSPL; ++sp) {
        m[sp]  = mlp[sp*64 + l31];
        lv[sp] = mlp[sp*64 + 32 + l31];
        M = fmaxf(M, m[sp]);
    }
    float wgt[NSPL], L = 0.f;
    #pragma unroll
    for (int sp = 0; sp < NSPL; ++sp) {
        wgt[sp] = fexp2(m[sp] - M);
        L += lv[sp] * wgt[sp];
    }
    float inv = 1.f / L;

    const float* op0 = Opart + (size_t)inst*NSPL*2048;
    float* outp = out + ((size_t)(b*S_ + q))*D_ + h*DH_;

    #pragma unroll
    for (int g = 0; g < 8; ++g) {
        v4f acc;
        #pragma unroll
        for (int jj = 0; jj < 4; ++jj) {
            int r = g*4 + jj;
            float v = 0.f;
            #pragma unroll
            for (int sp = 0; sp < NSPL; ++sp)
                v += op0[sp*2048 + r*64 + l] * wgt[sp];
            acc[jj] = v * inv;
        }
        int td = g >> 2, gg = g & 3;
        int d = td*32 + gg*8 + lhi*4;
        *(v4f*)(outp + d) = acc;
    }
}

extern "C" void kernel_launch(void* const* d_in, const int* in_sizes, int n_in,
                              void* d_out, int out_size, void* d_ws, size_t ws_size,
                              hipStream_t stream)
{
    const float* x  = (const float*)d_in[0];
    const float* qw = (const float*)d_in[1];
    const float* qb = (const float*)d_in[2];
    const float* kw = (const float*)d_in[3];
    const float* kb = (const float*)d_in[4];
    const float* vw = (const float*)d_in[5];
    const float* vb = (const float*)d_in[6];

    short* Qb  = (short*)d_ws;
    short* Kb  = Qb + NTOK;
    short* Vtb = Kb + NTOK;
    float* Opart = (float*)(Vtb + NTOK);

    // choose KV-split by workspace budget (prefer 4: 2 blocks/CU)
    size_t base = (size_t)3*NTOK*sizeof(short);
    size_t per_spl = (size_t)NINST*2048*4 + (size_t)NINST*64*4;
    int nspl = 1;
    if      (ws_size >= base + 4*per_spl) nspl = 4;
    else if (ws_size >= base + 2*per_spl) nspl = 2;
    float* Ml = Opart + (size_t)NINST*nspl*2048;
    int kvlen = S_/nspl;

    float* out = (float*)d_out;

    dim3 pg(S_/32, BH_), pb(256);
    hipLaunchKernelGGL(qkv_proj_kernel, pg, pb, 0, stream,
                       x, qw, qb, kw, kb, vw, vb, Qb, Kb, Vtb);

    dim3 ag(S_/QB, BH_, nspl), ab(512);
    hipLaunchKernelGGL(attn_kernel, ag, ab, 0, stream, Qb, Kb, Vtb, Opart, Ml, nspl, kvlen);

    dim3 cg(NINST/4), cb(256);
    if (nspl == 4)
        hipLaunchKernelGGL(combine_kernel<4>, cg, cb, 0, stream, Opart, Ml, out);
    else if (nspl == 2)
        hipLaunchKernelGGL(combine_kernel<2>, cg, cb, 0, stream, Opart, Ml, out);
    else
        hipLaunchKernelGGL(combine_kernel<1>, cg, cb, 0, stream, Opart, Ml, out);
}

// Round 5
// 73.975 us; speedup vs baseline: 3.3841x; 1.0303x over previous
//
#include <hip/hip_runtime.h>
#include <hip/hip_bf16.h>

// MSA: B=2, S=4096, D=256, H=4, DH=64. fp32 in/out, bf16 MFMA internally.
// R5: (a) MFMA-based QKV projection (was fp32 VALU, ~17us -> ~5us)
//     (b) attn: 4-buffer LDS + barrier every 2 tiles + global_load_lds
//         direct staging (T3 pipeline; removes reg-roundtrip + per-tile
//         lockstep). Softmax/pack/defer-max structure from R4 unchanged.

#define B_   2
#define S_   4096
#define D_   256
#define H_   4
#define DH_  64
#define BH_  8
#define NTOK (BH_*S_*DH_)   // elements per Q/K/V buffer

#define KVB  64             // kv tile per step
#define QW   32             // q rows per wave
#define NW   8              // waves per block
#define QB   (QW*NW)        // 256 q rows per block
#define NINST (BH_*(S_/QW)) // 1024 q-wave instances

typedef short v8s __attribute__((ext_vector_type(8)));
typedef float v16f __attribute__((ext_vector_type(16)));
typedef float v4f __attribute__((ext_vector_type(4)));
typedef unsigned v4u __attribute__((ext_vector_type(4)));
typedef unsigned v2u __attribute__((ext_vector_type(2)));
typedef int v2i __attribute__((ext_vector_type(2)));

#define QSCL (0.125f * 1.4426950408889634f)   // 1/sqrt(64) * log2(e): exp2 domain
#define DEFER_THR 8.0f                        // T13: P bounded by 2^8

static __device__ __forceinline__ short f2bf(float f) {
    __hip_bfloat16 h = __float2bfloat16(f);
    return *reinterpret_cast<short*>(&h);
}
static __device__ __forceinline__ unsigned cvtpk(float lo, float hi) {
    unsigned r;
    asm("v_cvt_pk_bf16_f32 %0, %1, %2" : "=v"(r) : "v"(lo), "v"(hi));
    return r;
}
// Raw v_exp_f32: args are <=0 finite; denormal flush acceptable here.
static __device__ __forceinline__ float fexp2(float x) {
#if __has_builtin(__builtin_amdgcn_exp2f)
    return __builtin_amdgcn_exp2f(x);
#else
    float r;
    asm("v_exp_f32 %0, %1" : "=v"(r) : "v"(x));
    return r;
#endif
}
static __device__ __forceinline__ float max3f(float a, float b, float c) {
    return fmaxf(fmaxf(a, b), c);   // clang fuses to v_max3_f32
}
static __device__ __forceinline__ void pl32swap(unsigned &a, unsigned &b) {
#if __has_builtin(__builtin_amdgcn_permlane32_swap)
    v2i r = __builtin_amdgcn_permlane32_swap((int)a, (int)b, false, false);
    a = (unsigned)r[0]; b = (unsigned)r[1];
#else
    asm volatile("v_permlane32_swap_b32 %0, %1" : "+v"(a), "+v"(b));
#endif
}
// Direct global->LDS staging: LDS dest = uniform base + lane*16 (linear),
// global src per-lane (carries the T2 pre-swizzle). Legal per m97/m104.
static __device__ __forceinline__ void gl2lds(const short* g, short* l) {
    __builtin_amdgcn_global_load_lds(
        (const __attribute__((address_space(1))) void*)g,
        (__attribute__((address_space(3))) void*)l, 16, 0, 0);
}
static __device__ __forceinline__ v16f vz16() {
    v16f z;
    #pragma unroll
    for (int i = 0; i < 16; ++i) z[i] = 0.f;
    return z;
}
static __device__ __forceinline__ v8s cvt8(const float* p) {
    v4f f0 = *(const v4f*)(p);
    v4f f1 = *(const v4f*)(p + 4);
    v4u u = { cvtpk(f0[0], f0[1]), cvtpk(f0[2], f0[3]),
              cvtpk(f1[0], f1[1]), cvtpk(f1[2], f1[3]) };
    return __builtin_bit_cast(v8s, u);
}

// ---------------------------------------------------------------------------
// Kernel 1: MFMA QKV projection. Block = 128 thr (2 waves), grid (128, BH).
// Wave w covers s-rows [blk*32, +32), units u = w*3..w*3+2 where
// u -> (p = u>>1, eb = u&1): p in {q,k,v}, eb = e-halfblock (e = eb*32+l31).
// mfma(A = X[32s x 16d], B = W^T[16d x 32e]) -> D[row=s][col=e].
//   Q: [BH][S][DH] pre-scaled by QSCL; K: [BH][S][DH]; Vt: [BH][DH][S].
// ---------------------------------------------------------------------------
__global__ __launch_bounds__(128) void qkv_proj_mfma(
    const float* __restrict__ x,
    const float* __restrict__ qw, const float* __restrict__ qb,
    const float* __restrict__ kw, const float* __restrict__ kb,
    const float* __restrict__ vw, const float* __restrict__ vb,
    short* __restrict__ Qo, short* __restrict__ Ko, short* __restrict__ Vt)
{
    const int t   = threadIdx.x;
    const int w   = t >> 6;
    const int l   = t & 63;
    const int l31 = l & 31, lhi = l >> 5;
    const int bh  = blockIdx.y, h = bh & 3, b = bh >> 2;
    const int s0  = blockIdx.x * 32;

    // A-frags from X (fp32 -> bf16): A[row=l31][k = k0*16 + lhi*8 + j]
    const float* xrow = x + ((size_t)(b*S_ + s0 + l31))*D_ + h*DH_;
    v8s af[4];
    #pragma unroll
    for (int k0 = 0; k0 < 4; ++k0)
        af[k0] = cvt8(xrow + k0*16 + lhi*8);

    const float* Wp[3] = { qw + h*DH_*DH_, kw + h*DH_*DH_, vw + h*DH_*DH_ };
    const float* Bp[3] = { qb + h*DH_,     kb + h*DH_,     vb + h*DH_ };
    short* Qh = Qo + (size_t)bh*S_*DH_;
    short* Kh = Ko + (size_t)bh*S_*DH_;

    #pragma unroll
    for (int ui = 0; ui < 3; ++ui) {
        const int u  = w*3 + ui;
        const int p  = u >> 1;
        const int eb = u & 1;
        const int e  = eb*32 + l31;
        const float* wrow = Wp[p] + e*DH_;     // W[e][d] row-major

        v16f acc = vz16();
        #pragma unroll
        for (int k0 = 0; k0 < 4; ++k0) {
            v8s bfr = cvt8(wrow + k0*16 + lhi*8);  // B[col=e][k]
            acc = __builtin_amdgcn_mfma_f32_32x32x16_bf16(af[k0], bfr, acc, 0, 0, 0);
        }

        const float bias = Bp[p][e];
        if (p == 0) {
            const float bq = bias * QSCL;
            #pragma unroll
            for (int r = 0; r < 16; ++r) acc[r] = fmaf(acc[r], QSCL, bq);
        } else {
            #pragma unroll
            for (int r = 0; r < 16; ++r) acc[r] += bias;
        }

        if (p < 2) {
            short* dst = (p == 0) ? Qh : Kh;
            #pragma unroll
            for (int r = 0; r < 16; ++r) {
                int s = s0 + (r & 3) + 8*(r >> 2) + 4*lhi;
                dst[(size_t)s*DH_ + e] = f2bf(acc[r]);
            }
        } else {
            short* vtb = Vt + (size_t)bh*DH_*S_ + (size_t)e*S_;
            #pragma unroll
            for (int rq = 0; rq < 4; ++rq) {
                v2u pr = { cvtpk(acc[rq*4+0], acc[rq*4+1]),
                           cvtpk(acc[rq*4+2], acc[rq*4+3]) };
                int s = s0 + rq*8 + 4*lhi;           // 4 consecutive s
                *(v2u*)(vtb + s) = pr;
            }
        }
    }
}

// ---------------------------------------------------------------------------
// Kernel 2: flash attention, swapped QK^T, 32x32x16 MFMA.
// 4-buffer LDS, global_load_lds staging (prefetch distance 2), barrier
// every 2 tiles -> waves skew within a 2-tile window (VALU/MFMA overlap).
// Fragment layouts (32x32x16, m74/m101):
//   A: row=lane&31, k=(lane>>5)*8+j ; B: col=lane&31, k=(lane>>5)*8+j
//   C/D: col=lane&31, row=(reg&3)+8*(reg>>2)+4*(lane>>5)
// LDS tiles [64 rows][8 chunks of 16B], phys chunk = logical ^ (row&7)
// (T2), realized by pre-swizzled GLOBAL source + swizzled ds_read address.
// ---------------------------------------------------------------------------
__global__ __launch_bounds__(512, 4) void attn_kernel(
    const short* __restrict__ Q, const short* __restrict__ K,
    const short* __restrict__ Vt, float* __restrict__ Opart,
    float* __restrict__ Ml, int nspl, int kvlen)
{
    __shared__ __align__(16) short klds[4][64][64];
    __shared__ __align__(16) short vlds[4][64][64];

    const int t    = threadIdx.x;
    const int w    = t >> 6;
    const int l    = t & 63;
    const int l31  = l & 31;
    const int lhi  = l >> 5;
    const int bh   = blockIdx.y;
    const int qtil = blockIdx.x;
    const int spl  = blockIdx.z;
    const int q0   = qtil*QB + w*QW;
    const int kv_beg = spl * kvlen;

    const short* Qh = Q  + (size_t)bh*S_*DH_;
    const short* Kh = K  + (size_t)bh*S_*DH_;
    const short* Vh = Vt + (size_t)bh*DH_*S_;

    // staging geometry: wave w stages rows w*8..w*8+7 of each 64-row tile.
    // lane l -> row w*8 + (l>>3), phys chunk l&7; source chunk pre-swizzled.
    const int rl  = l >> 3;
    const int cs  = (l & 7) ^ (rl & 7);
    const size_t koff = (size_t)(w*8 + rl)*DH_ + cs*8;
    const size_t voff = (size_t)(w*8 + rl)*S_  + cs*8;
    short* kls = (short*)klds + w*512;   // + buf*4096
    short* vls = (short*)vlds + w*512;

    // Q B-frags (per-wave constant): q=q0+l31, dh = k0*16 + lhi*8 + j
    v8s qf[4];
    #pragma unroll
    for (int k0 = 0; k0 < 4; ++k0)
        qf[k0] = *(const v8s*)(Qh + (size_t)(q0 + l31)*DH_ + k0*16 + lhi*8);

    // swizzled frag-read offsets: fo[tile-half][chunkpair]
    int fo[2][4];
    #pragma unroll
    for (int a = 0; a < 2; ++a)
        #pragma unroll
        for (int c = 0; c < 4; ++c)
            fo[a][c] = (a*32 + l31)*64 + (((c*2 + lhi) ^ (l31 & 7))*8);

    v16f o0 = vz16(), o1 = vz16();
    float m_run = -INFINITY, l_run = 0.f;

    const int NT = kvlen / KVB;

    auto stage = [&](int tile, int buf) {
        const size_t kvo = kv_beg + (size_t)tile*KVB;
        gl2lds(Kh + kvo*DH_ + koff, kls + buf*4096);
        gl2lds(Vh + kvo      + voff, vls + buf*4096);
    };

    auto tilebody = [&](int buf) {
        const short* kb = (const short*)klds + buf*4096;
        const short* vb = (const short*)vlds + buf*4096;

        // --- QK^T (swapped): S^T[kv][q], 2 kv-halves of 32 ---
        v16f s0 = vz16(), s1 = vz16();
        __builtin_amdgcn_s_setprio(1);
        #pragma unroll
        for (int k0 = 0; k0 < 4; ++k0) {
            v8s a0 = *(const v8s*)(kb + fo[0][k0]);
            v8s a1 = *(const v8s*)(kb + fo[1][k0]);
            s0 = __builtin_amdgcn_mfma_f32_32x32x16_bf16(a0, qf[k0], s0, 0, 0, 0);
            s1 = __builtin_amdgcn_mfma_f32_32x32x16_bf16(a1, qf[k0], s1, 0, 0, 0);
        }
        __builtin_amdgcn_s_setprio(0);

        // --- online softmax (exp2 domain), max3 tree + defer-max ---
        float t16[16];
        #pragma unroll
        for (int i = 0; i < 16; ++i) t16[i] = fmaxf(s0[i], s1[i]);
        float r0 = max3f(t16[0],  t16[1],  t16[2]);
        float r1 = max3f(t16[3],  t16[4],  t16[5]);
        float r2 = max3f(t16[6],  t16[7],  t16[8]);
        float r3 = max3f(t16[9],  t16[10], t16[11]);
        float r4 = max3f(t16[12], t16[13], t16[14]);
        float mx = fmaxf(max3f(max3f(r0, r1, r2), r3, r4), t16[15]);
        mx = fmaxf(mx, __shfl_xor(mx, 32));

        if (__any(mx > m_run + DEFER_THR)) {     // T13: rarely taken after tile 0
            float mn = fmaxf(m_run, mx);
            float sc = fexp2(m_run - mn);
            #pragma unroll
            for (int i = 0; i < 16; ++i) { o0[i] *= sc; o1[i] *= sc; }
            l_run *= sc;
            m_run = mn;
        }
        #pragma unroll
        for (int i = 0; i < 16; ++i) s0[i] = fexp2(s0[i] - m_run);
        #pragma unroll
        for (int i = 0; i < 16; ++i) s1[i] = fexp2(s1[i] - m_run);
        float a16[16];
        #pragma unroll
        for (int i = 0; i < 16; ++i) a16[i] = s0[i] + s1[i];
        #pragma unroll
        for (int st = 8; st; st >>= 1)
            #pragma unroll
            for (int i = 0; i < st; ++i) a16[i] += a16[i+st];
        l_run += a16[0] + __shfl_xor(a16[0], 32);

        // --- pack P -> 4 PV B-frags (T12: cvt_pk + permlane32_swap) ---
        unsigned pwv[4][4];
        {
            unsigned j0 = cvtpk(s0[0], s0[1]),  j1 = cvtpk(s0[2], s0[3]);
            unsigned j2 = cvtpk(s0[4], s0[5]),  j3 = cvtpk(s0[6], s0[7]);
            unsigned j4 = cvtpk(s0[8], s0[9]),  j5 = cvtpk(s0[10], s0[11]);
            unsigned j6 = cvtpk(s0[12], s0[13]), j7 = cvtpk(s0[14], s0[15]);
            pl32swap(j0, j2); pl32swap(j1, j3);
            pwv[0][0] = j0; pwv[0][1] = j1; pwv[0][2] = j2; pwv[0][3] = j3;
            pl32swap(j4, j6); pl32swap(j5, j7);
            pwv[1][0] = j4; pwv[1][1] = j5; pwv[1][2] = j6; pwv[1][3] = j7;
        }
        {
            unsigned j0 = cvtpk(s1[0], s1[1]),  j1 = cvtpk(s1[2], s1[3]);
            unsigned j2 = cvtpk(s1[4], s1[5]),  j3 = cvtpk(s1[6], s1[7]);
            unsigned j4 = cvtpk(s1[8], s1[9]),  j5 = cvtpk(s1[10], s1[11]);
            unsigned j6 = cvtpk(s1[12], s1[13]), j7 = cvtpk(s1[14], s1[15]);
            pl32swap(j0, j2); pl32swap(j1, j3);
            pwv[2][0] = j0; pwv[2][1] = j1; pwv[2][2] = j2; pwv[2][3] = j3;
            pl32swap(j4, j6); pl32swap(j5, j7);
            pwv[3][0] = j4; pwv[3][1] = j5; pwv[3][2] = j6; pwv[3][3] = j7;
        }

        // --- PV: O^T[d][q] += V^T[d][kv] * P^T[kv][q] ---
        __builtin_amdgcn_s_setprio(1);
        #pragma unroll
        for (int kk = 0; kk < 4; ++kk) {
            v4u u = { pwv[kk][0], pwv[kk][1], pwv[kk][2], pwv[kk][3] };
            v8s pf = __builtin_bit_cast(v8s, u);
            v8s va0 = *(const v8s*)(vb + fo[0][kk]);
            v8s va1 = *(const v8s*)(vb + fo[1][kk]);
            o0 = __builtin_amdgcn_mfma_f32_32x32x16_bf16(va0, pf, o0, 0, 0, 0);
            o1 = __builtin_amdgcn_mfma_f32_32x32x16_bf16(va1, pf, o1, 0, 0, 0);
        }
        __builtin_amdgcn_s_setprio(0);
    };

    // prologue: stage tiles 0,1 into bufs 0,1 (syncthreads drains vmcnt)
    stage(0, 0);
    stage(1, 1);
    __syncthreads();

    for (int it = 0; it < NT; it += 2) {
        if (it + 2 < NT) stage(it + 2, (it + 2) & 3);
        tilebody(it & 3);
        if (it + 3 < NT) stage(it + 3, (it + 3) & 3);
        tilebody((it + 1) & 3);
        __syncthreads();   // drains vmcnt(0): staged tiles complete + visible
    }

    // --- epilogue: dump unnormalized O^T (reg order) + m/l ---
    const int inst = bh*(S_/QW) + qtil*NW + w;
    float* od = Opart + ((size_t)inst*nspl + spl)*2048;
    #pragma unroll
    for (int r = 0; r < 16; ++r) od[r*64 + l]      = o0[r];
    #pragma unroll
    for (int r = 0; r < 16; ++r) od[(16+r)*64 + l] = o1[r];
    Ml[((size_t)inst*nspl + spl)*64 + l] = (l < 32) ? m_run : l_run;
}

// ---------------------------------------------------------------------------
// Kernel 3: merge KV-split partials, normalize, write fp32 out [B][S][D].
// ---------------------------------------------------------------------------
template<int NSPL>
__global__ __launch_bounds__(256) void combine_kernel(
    const float* __restrict__ Opart, const float* __restrict__ Ml,
    float* __restrict__ out)
{
    const int t = threadIdx.x;
    const int w = t >> 6, l = t & 63;
    const int inst = blockIdx.x*4 + w;
    const int bh = inst >> 7;           // / (S_/QW = 128)
    const int qw = inst & 127;
    const int b = bh >> 2, h = bh & 3;
    const int l31 = l & 31, lhi = l >> 5;
    const int q = qw*32 + l31;

    const float* mlp = Ml + (size_t)inst*NSPL*64;
    float m[NSPL], lv[NSPL];
    float M = -INFINITY;
    #pragma unroll
    for (int sp = 0; sp < NSPL; ++sp) {
        m[sp]  = mlp[sp*64 + l31];
        lv[sp] = mlp[sp*64 + 32 + l31];
        M = fmaxf(M, m[sp]);
    }
    float wgt[NSPL], L = 0.f;
    #pragma unroll
    for (int sp = 0; sp < NSPL; ++sp) {
        wgt[sp] = fexp2(m[sp] - M);
        L += lv[sp] * wgt[sp];
    }
    float inv = 1.f / L;

    const float* op0 = Opart + (size_t)inst*NSPL*2048;
    float* outp = out + ((size_t)(b*S_ + q))*D_ + h*DH_;

    #pragma unroll
    for (int g = 0; g < 8; ++g) {
        v4f acc;
        #pragma unroll
        for (int jj = 0; jj < 4; ++jj) {
            int r = g*4 + jj;
            float v = 0.f;
            #pragma unroll
            for (int sp = 0; sp < NSPL; ++sp)
                v += op0[sp*2048 + r*64 + l] * wgt[sp];
            acc[jj] = v * inv;
        }
        int td = g >> 2, gg = g & 3;
        int d = td*32 + gg*8 + lhi*4;
        *(v4f*)(outp + d) = acc;
    }
}

extern "C" void kernel_launch(void* const* d_in, const int* in_sizes, int n_in,
                              void* d_out, int out_size, void* d_ws, size_t ws_size,
                              hipStream_t stream)
{
    const float* x  = (const float*)d_in[0];
    const float* qw = (const float*)d_in[1];
    const float* qb = (const float*)d_in[2];
    const float* kw = (const float*)d_in[3];
    const float* kb = (const float*)d_in[4];
    const float* vw = (const float*)d_in[5];
    const float* vb = (const float*)d_in[6];

    short* Qb  = (short*)d_ws;
    short* Kb  = Qb + NTOK;
    short* Vtb = Kb + NTOK;
    float* Opart = (float*)(Vtb + NTOK);

    // choose KV-split by workspace budget (prefer 4: 2 blocks/CU)
    size_t base = (size_t)3*NTOK*sizeof(short);
    size_t per_spl = (size_t)NINST*2048*4 + (size_t)NINST*64*4;
    int nspl = 1;
    if      (ws_size >= base + 4*per_spl) nspl = 4;
    else if (ws_size >= base + 2*per_spl) nspl = 2;
    float* Ml = Opart + (size_t)NINST*nspl*2048;
    int kvlen = S_/nspl;

    float* out = (float*)d_out;

    dim3 pg(S_/32, BH_), pb(128);
    hipLaunchKernelGGL(qkv_proj_mfma, pg, pb, 0, stream,
                       x, qw, qb, kw, kb, vw, vb, Qb, Kb, Vtb);

    dim3 ag(S_/QB, BH_, nspl), ab(512);
    hipLaunchKernelGGL(attn_kernel, ag, ab, 0, stream, Qb, Kb, Vtb, Opart, Ml, nspl, kvlen);

    dim3 cg(NINST/4), cb(256);
    if (nspl == 4)
        hipLaunchKernelGGL(combine_kernel<4>, cg, cb, 0, stream, Opart, Ml, out);
    else if (nspl == 2)
        hipLaunchKernelGGL(combine_kernel<2>, cg, cb, 0, stream, Opart, Ml, out);
    else
        hipLaunchKernelGGL(combine_kernel<1>, cg, cb, 0, stream, Opart, Ml, out);
}